// Round 10
// baseline (33.015 us; speedup 1.0000x reference)
//
#include <hip/hip_runtime.h>

#define B_SZ 512
#define V_SZ 1024
#define K_SZ 64
#define C_SZ 2048
#define A_SZ 128

#define LOG2E 1.4426950408889634f

// ---------------------------------------------------------------------------
// Fully fused: one block per 2 batch rows, 768 threads (12 waves).
// Phase 1: wave w -> matrix m=w>>2, v-quarter q=w&3; lane = k.
//   x is read via SCALAR loads (wave-uniform address -> s_load, constant
//   cache) -- no LDS in the inner loop (the R8 ds_read stream was ~7.7us of
//   serialized LDS-pipe occupancy). Per iter: s_load'd x pair + 1 coalesced
//   W load + 2 FMA. LDS reduce of the 4 v-quarters afterward.
// Phase 2 (verbatim R8): cutoff CL (term <= 2^-150), phi -> LDS+global,
//   exact zeros beyond, window = phi[0:CL) @ text[0:CL).
// ---------------------------------------------------------------------------
__global__ __launch_bounds__(768) void gw_fused(
    const float* __restrict__ x, const float* __restrict__ text,
    const float* __restrict__ prev_kappa,
    const float* __restrict__ Wa, const float* __restrict__ ba,
    const float* __restrict__ Wb, const float* __restrict__ bb,
    const float* __restrict__ Wk, const float* __restrict__ bk,
    float* __restrict__ out_phi, float* __restrict__ out_kappa,
    float* __restrict__ out_window) {
  __shared__ float part[12][2][K_SZ];     // 6KB  [wave][row][k]
  __shared__ float al[2][K_SZ];
  __shared__ float bn[2][K_SZ];           // -log2(e)*beta
  __shared__ float kap[2][K_SZ];
  __shared__ float bnd[2][K_SZ];
  __shared__ int cl_s[2];
  __shared__ float phi_s[2][C_SZ];        // 16KB
  __shared__ float4 red[2][12][32];       // 12KB

  const int tid = threadIdx.x;
  const int b0 = blockIdx.x * 2;

  // ---- Phase 1: GEMM, scalar-x inner loop ----
  {
    const int w = tid >> 6;     // wave 0..11
    const int m = w >> 2;       // 0=alpha, 1=beta, 2=kappa
    const int q = w & 3;        // v-quarter
    const int k = tid & 63;
    const float* __restrict__ Wm = (m == 0) ? Wa : (m == 1) ? Wb : Wk;
    const float* __restrict__ x0 = x + (size_t)b0 * V_SZ;   // uniform
    const float* __restrict__ x1 = x0 + V_SZ;

    float acc0 = 0.f, acc1 = 0.f;
    const int v0 = q * 256;
#pragma unroll 16
    for (int v = v0; v < v0 + 256; ++v) {
      float wv = Wm[v * K_SZ + k];    // 256B coalesced vector load
      float xv0 = x0[v];              // wave-uniform -> s_load (K$ pipe)
      float xv1 = x1[v];
      acc0 = fmaf(xv0, wv, acc0);
      acc1 = fmaf(xv1, wv, acc1);
    }
    part[w][0][k] = acc0;
    part[w][1][k] = acc1;
  }
  __syncthreads();

  if (tid < 384) {
    const int mm = tid >> 7;         // 0=alpha, 1=beta, 2=kappa
    const int r = (tid >> 6) & 1;
    const int kk = tid & 63;
    float s = part[mm * 4 + 0][r][kk] + part[mm * 4 + 1][r][kk] +
              part[mm * 4 + 2][r][kk] + part[mm * 4 + 3][r][kk];
    const float bias = ((mm == 0) ? ba : (mm == 1) ? bb : bk)[kk];
    const float e = expf(s + bias);
    if (mm == 0) {
      al[r][kk] = e;
    } else if (mm == 1) {
      bn[r][kk] = -LOG2E * e;
    } else {
      float nk = prev_kappa[(b0 + r) * K_SZ + kk] + e;
      kap[r][kk] = nk;
      out_kappa[(b0 + r) * K_SZ + kk] = nk;
    }
  }
  __syncthreads();

  // ---- cutoff per row: term <= 2^-150 for c >= bnd ----
  if (tid < 128) {
    const int r = tid >> 6, kk = tid & 63;
    float num = 150.f + fmaxf(0.f, log2f(al[r][kk]));
    bnd[r][kk] = kap[r][kk] + sqrtf(num / (-bn[r][kk]));
  }
  __syncthreads();
  if (tid < 2) {
    float mx = 0.f;
    for (int i = 0; i < K_SZ; ++i) mx = fmaxf(mx, bnd[tid][i]);
    mx = fminf(mx, (float)C_SZ);     // sanitizes inf -> full compute
    int cl = (int)mx + 1;
    cl = (cl + 15) & ~15;
    if (cl > C_SZ) cl = C_SZ;
    cl_s[tid] = cl;
  }
  __syncthreads();

  // ---- Phase 2: halves (wave-aligned) own one row each ----
  const int half = tid / 384;        // 0 or 1
  const int t2 = tid - half * 384;   // 0..383
  const int r = half;
  const int b = b0 + r;
  const int CL = cl_s[r];

  // phi for c < CL
  for (int c = t2; c < CL; c += 384) {
    float cf = (float)c;
    float s = 0.f;
#pragma unroll
    for (int kk = 0; kk < K_SZ; ++kk) {
      float d = kap[r][kk] - cf;
      s += al[r][kk] * exp2f(bn[r][kk] * d * d);
    }
    phi_s[r][c] = s;
    out_phi[(size_t)b * C_SZ + c] = s;
  }
  // exact zeros for c >= CL
  {
    float4 z = make_float4(0.f, 0.f, 0.f, 0.f);
    float4* po = (float4*)(out_phi + (size_t)b * C_SZ);
    for (int i = (CL >> 2) + t2; i < C_SZ / 4; i += 384) po[i] = z;
  }
  __syncthreads();

  // window over [0, CL) rows of text
  {
    const float4* __restrict__ t4 =
        (const float4*)(text + (size_t)b * C_SZ * A_SZ);
    const int a4 = t2 & 31;   // float4 column (covers A=128)
    const int cr = t2 >> 5;   // 12 parallel c-rows per half

    float4 acc = make_float4(0.f, 0.f, 0.f, 0.f);
    for (int cc = cr; cc < CL; cc += 12) {
      float p = phi_s[r][cc];
      float4 t = t4[cc * 32 + a4];   // coalesced 512B per row
      acc.x = fmaf(p, t.x, acc.x);
      acc.y = fmaf(p, t.y, acc.y);
      acc.z = fmaf(p, t.z, acc.z);
      acc.w = fmaf(p, t.w, acc.w);
    }
    red[r][cr][a4] = acc;
  }
  __syncthreads();

  if (t2 < 32) {
    float4 wv = red[r][0][t2];
#pragma unroll
    for (int i = 1; i < 12; ++i) {
      float4 rr = red[r][i][t2];
      wv.x += rr.x; wv.y += rr.y; wv.z += rr.z; wv.w += rr.w;
    }
    ((float4*)(out_window + (size_t)b * A_SZ))[t2] = wv;
  }
}

extern "C" void kernel_launch(void* const* d_in, const int* in_sizes, int n_in,
                              void* d_out, int out_size, void* d_ws, size_t ws_size,
                              hipStream_t stream) {
  const float* x    = (const float*)d_in[0];
  const float* text = (const float*)d_in[1];
  const float* pk   = (const float*)d_in[2];
  const float* Wa   = (const float*)d_in[3];
  const float* ba   = (const float*)d_in[4];
  const float* Wb   = (const float*)d_in[5];
  const float* bb   = (const float*)d_in[6];
  const float* Wk   = (const float*)d_in[7];
  const float* bk   = (const float*)d_in[8];

  float* out        = (float*)d_out;
  float* out_phi    = out;                              // B*C
  float* out_kappa  = out + (size_t)B_SZ * C_SZ;        // B*K
  float* out_win    = out_kappa + (size_t)B_SZ * K_SZ;  // B*A

  gw_fused<<<B_SZ / 2, 768, 0, stream>>>(x, text, pk, Wa, ba, Wb, bb, Wk, bk,
                                         out_phi, out_kappa, out_win);
}

// Round 11
// 21.484 us; speedup vs baseline: 1.5367x; 1.5367x over previous
//
#include <hip/hip_runtime.h>

#define B_SZ 512
#define V_SZ 1024
#define K_SZ 64
#define C_SZ 2048
#define A_SZ 128

#define LOG2E 1.4426950408889634f

// ---------------------------------------------------------------------------
// Fully fused: one block per 2 batch rows, 768 threads (12 waves).
// Phase 1 (wide-load GEMM): wave w -> matrix m=w>>2, v-quarter q=w&3.
//   Each iter: ONE global_load_dwordx4 per lane covers 4 W-rows per wave
//   (1KB contiguous: lane l -> row v0+(l>>4), cols 4(l&15)..+3), one
//   ds_read_b64 of the x row-pair (4 distinct addrs, 16-lane broadcast),
//   8 FMAs. 64 iters/wave -> VMEM instr count 4x lower than R8 (the
//   measured binding resource). Epilogue: shfl_xor(16,32) folds the 4
//   v-phases; lanes 0-15 hold 4 cols each; LDS reduce over v-quarters.
// Phase 2 (verbatim R8): cutoff CL (term <= 2^-150), phi -> LDS+global,
//   exact zeros beyond, window = phi[0:CL) @ text[0:CL).
// ---------------------------------------------------------------------------
__global__ __launch_bounds__(768) void gw_fused(
    const float* __restrict__ x, const float* __restrict__ text,
    const float* __restrict__ prev_kappa,
    const float* __restrict__ Wa, const float* __restrict__ ba,
    const float* __restrict__ Wb, const float* __restrict__ bb,
    const float* __restrict__ Wk, const float* __restrict__ bk,
    float* __restrict__ out_phi, float* __restrict__ out_kappa,
    float* __restrict__ out_window) {
  __shared__ float2 xs2[V_SZ];            // 8KB  {row0[v], row1[v]}
  __shared__ float part[12][2][K_SZ];     // 6KB  [wave][row][k]
  __shared__ float al[2][K_SZ];
  __shared__ float bn[2][K_SZ];           // -log2(e)*beta
  __shared__ float kap[2][K_SZ];
  __shared__ float bnd[2][K_SZ];
  __shared__ int cl_s[2];
  __shared__ float phi_s[2][C_SZ];        // 16KB
  __shared__ float4 red[2][12][32];       // 12KB

  const int tid = threadIdx.x;
  const int b0 = blockIdx.x * 2;

  // ---- stage x row pair ----
  {
    const float* x0 = x + (size_t)b0 * V_SZ;
    const float* x1 = x0 + V_SZ;
    for (int i = tid; i < V_SZ; i += 768)
      xs2[i] = make_float2(x0[i], x1[i]);   // coalesced sweeps
  }
  __syncthreads();

  // ---- Phase 1: GEMM, wide W loads ----
  {
    const int w = tid >> 6;       // wave 0..11
    const int m = w >> 2;         // 0=alpha, 1=beta, 2=kappa
    const int q = w & 3;          // v-quarter
    const int l = tid & 63;       // lane
    const int vr_off = l >> 4;    // which of 4 rows this lane covers
    const int cg = l & 15;        // col group: cols 4cg..4cg+3
    const float* __restrict__ Wm = (m == 0) ? Wa : (m == 1) ? Wb : Wk;
    const float4* __restrict__ Wm4 = (const float4*)Wm;  // 16 float4 per row

    float a0x = 0.f, a0y = 0.f, a0z = 0.f, a0w = 0.f;   // row0, 4 cols
    float a1x = 0.f, a1y = 0.f, a1z = 0.f, a1w = 0.f;   // row1, 4 cols
    const int v0 = q * 256;
#pragma unroll 8
    for (int t = 0; t < 64; ++t) {
      const int vr = v0 + 4 * t + vr_off;
      float4 wv = Wm4[vr * 16 + cg];      // 1KB contiguous per wave
      float2 xv = xs2[vr];                // 4 addrs, 16-lane broadcast
      a0x = fmaf(xv.x, wv.x, a0x); a1x = fmaf(xv.y, wv.x, a1x);
      a0y = fmaf(xv.x, wv.y, a0y); a1y = fmaf(xv.y, wv.y, a1y);
      a0z = fmaf(xv.x, wv.z, a0z); a1z = fmaf(xv.y, wv.z, a1z);
      a0w = fmaf(xv.x, wv.w, a0w); a1w = fmaf(xv.y, wv.w, a1w);
    }
    // fold the 4 v-phases (lanes l, l^16, l^32 hold same cols)
#pragma unroll
    for (int off = 16; off < 64; off <<= 1) {
      a0x += __shfl_xor(a0x, off); a0y += __shfl_xor(a0y, off);
      a0z += __shfl_xor(a0z, off); a0w += __shfl_xor(a0w, off);
      a1x += __shfl_xor(a1x, off); a1y += __shfl_xor(a1y, off);
      a1z += __shfl_xor(a1z, off); a1w += __shfl_xor(a1w, off);
    }
    if (l < 16) {
      *(float4*)&part[w][0][4 * cg] = make_float4(a0x, a0y, a0z, a0w);
      *(float4*)&part[w][1][4 * cg] = make_float4(a1x, a1y, a1z, a1w);
    }
  }
  __syncthreads();

  if (tid < 384) {
    const int mm = tid >> 7;         // 0=alpha, 1=beta, 2=kappa
    const int r = (tid >> 6) & 1;
    const int kk = tid & 63;
    float s = part[mm * 4 + 0][r][kk] + part[mm * 4 + 1][r][kk] +
              part[mm * 4 + 2][r][kk] + part[mm * 4 + 3][r][kk];
    const float bias = ((mm == 0) ? ba : (mm == 1) ? bb : bk)[kk];
    const float e = expf(s + bias);
    if (mm == 0) {
      al[r][kk] = e;
    } else if (mm == 1) {
      bn[r][kk] = -LOG2E * e;
    } else {
      float nk = prev_kappa[(b0 + r) * K_SZ + kk] + e;
      kap[r][kk] = nk;
      out_kappa[(b0 + r) * K_SZ + kk] = nk;
    }
  }
  __syncthreads();

  // ---- cutoff per row: term <= 2^-150 for c >= bnd ----
  if (tid < 128) {
    const int r = tid >> 6, kk = tid & 63;
    float num = 150.f + fmaxf(0.f, log2f(al[r][kk]));
    bnd[r][kk] = kap[r][kk] + sqrtf(num / (-bn[r][kk]));
  }
  __syncthreads();
  if (tid < 2) {
    float mx = 0.f;
    for (int i = 0; i < K_SZ; ++i) mx = fmaxf(mx, bnd[tid][i]);
    mx = fminf(mx, (float)C_SZ);     // sanitizes inf -> full compute
    int cl = (int)mx + 1;
    cl = (cl + 15) & ~15;
    if (cl > C_SZ) cl = C_SZ;
    cl_s[tid] = cl;
  }
  __syncthreads();

  // ---- Phase 2: halves (wave-aligned) own one row each ----
  const int half = tid / 384;        // 0 or 1
  const int t2 = tid - half * 384;   // 0..383
  const int r = half;
  const int b = b0 + r;
  const int CL = cl_s[r];

  // phi for c < CL
  for (int c = t2; c < CL; c += 384) {
    float cf = (float)c;
    float s = 0.f;
#pragma unroll
    for (int kk = 0; kk < K_SZ; ++kk) {
      float d = kap[r][kk] - cf;
      s += al[r][kk] * exp2f(bn[r][kk] * d * d);
    }
    phi_s[r][c] = s;
    out_phi[(size_t)b * C_SZ + c] = s;
  }
  // exact zeros for c >= CL
  {
    float4 z = make_float4(0.f, 0.f, 0.f, 0.f);
    float4* po = (float4*)(out_phi + (size_t)b * C_SZ);
    for (int i = (CL >> 2) + t2; i < C_SZ / 4; i += 384) po[i] = z;
  }
  __syncthreads();

  // window over [0, CL) rows of text
  {
    const float4* __restrict__ t4 =
        (const float4*)(text + (size_t)b * C_SZ * A_SZ);
    const int a4 = t2 & 31;   // float4 column (covers A=128)
    const int cr = t2 >> 5;   // 12 parallel c-rows per half

    float4 acc = make_float4(0.f, 0.f, 0.f, 0.f);
    for (int cc = cr; cc < CL; cc += 12) {
      float p = phi_s[r][cc];
      float4 t = t4[cc * 32 + a4];   // coalesced 512B per row
      acc.x = fmaf(p, t.x, acc.x);
      acc.y = fmaf(p, t.y, acc.y);
      acc.z = fmaf(p, t.z, acc.z);
      acc.w = fmaf(p, t.w, acc.w);
    }
    red[r][cr][a4] = acc;
  }
  __syncthreads();

  if (t2 < 32) {
    float4 wv = red[r][0][t2];
#pragma unroll
    for (int i = 1; i < 12; ++i) {
      float4 rr = red[r][i][t2];
      wv.x += rr.x; wv.y += rr.y; wv.z += rr.z; wv.w += rr.w;
    }
    ((float4*)(out_window + (size_t)b * A_SZ))[t2] = wv;
  }
}

extern "C" void kernel_launch(void* const* d_in, const int* in_sizes, int n_in,
                              void* d_out, int out_size, void* d_ws, size_t ws_size,
                              hipStream_t stream) {
  const float* x    = (const float*)d_in[0];
  const float* text = (const float*)d_in[1];
  const float* pk   = (const float*)d_in[2];
  const float* Wa   = (const float*)d_in[3];
  const float* ba   = (const float*)d_in[4];
  const float* Wb   = (const float*)d_in[5];
  const float* bb   = (const float*)d_in[6];
  const float* Wk   = (const float*)d_in[7];
  const float* bk   = (const float*)d_in[8];

  float* out        = (float*)d_out;
  float* out_phi    = out;                              // B*C
  float* out_kappa  = out + (size_t)B_SZ * C_SZ;        // B*K
  float* out_win    = out_kappa + (size_t)B_SZ * K_SZ;  // B*A

  gw_fused<<<B_SZ / 2, 768, 0, stream>>>(x, text, pk, Wa, ba, Wb, bb, Wk, bk,
                                         out_phi, out_kappa, out_win);
}